// Round 2
// 162.875 us; speedup vs baseline: 1.0029x; 1.0029x over previous
//
#include <hip/hip_runtime.h>
#include <stdint.h>
#include <stddef.h>

// RadialCTC: cosine logits (norm_scale=32) -> log_softmax -> CTC(sum).
// Strategy: never materialize the (16384 x 1296) logits. GEMM (f16 MFMA)
// computes per-row sum(exp(logit)) fused in the epilogue; label log-probs via
// small f16 MFMA gather-GEMM; CTC alpha recursion one wave per sample.
// R4: gather on MFMA. R5: shfl=ds_bpermute ~120cyc; fp8 non-scaled = f16 rate.
// R6: DPP wave_shr neighbor access. R7: log-pair-fusion regressed. R8: linear
// f32 FAILED. R9: linear f64 + pow2 renorm: ~30us ctc. R10: profile showed
// gemm LDS 8-way conflicts. R11: XOR channel-slot swizzle (kept) -- but only
// ~1us total, so gemm was not the main slack.
// R12: node-count collapse 9 -> 4 dispatches. Budget arithmetic says ~45us of
// the 163 is inter-node gap (every kernel < 43us = harness fill time;
// kernel-sum estimate ~115us). Fused colnorm+wt+fnorm+memsets into one
// sectioned prep kernel (atomic-free W-norm, zeroes sumexp+ctr); fused reduce
// into ctc via fence+counter last-block pattern. gemm/gather untouched.
// R13: R12 bench died with "container failed twice" = broker/infra failure,
// not a verify failure. Audit found no OOB/hang path in the R12 diff
// (bounds re-checked, no spin-waits, ctr re-zeroed per launch). Resubmitting
// R12 unchanged. If it fails again -> suspect ctc fused-reduce, revert that.

typedef _Float16 f16;
typedef _Float16 f16x8 __attribute__((ext_vector_type(8)));
typedef float f32x4 __attribute__((ext_vector_type(4)));
typedef __attribute__((address_space(1))) void* as1_void_ptr;
typedef __attribute__((address_space(3))) void* as3_void_ptr;

#define TT 512
#define NN 32
#define CC 1296
#define DD 512
#define SS 30
#define CP 1408   // C padded to 11*128 for GEMM tiling (pad rows are zero)
#define LL 61     // 2*S+1 CTC states
#define NEGINF (-1e9f)
#define NORM_SCALE 32.0f
#define LOG2E 1.4426950408889634f
#define LN2   0.6931471805599453f

#define PREP_WBLK (CP / 16)            // 88 c-tiles of 16 (covers pad -> zeros)
#define PREP_ZBLK 17                   // 16 zero sumexp + 1 zero counter
#define PREP_FBLK (TT * NN / 4)        // 4096 fnorm blocks (4 rows each)

__device__ __forceinline__ float fexp2(float x) { return __builtin_amdgcn_exp2f(x); }
__device__ __forceinline__ float flog2(float x) { return __builtin_amdgcn_logf(x); }

// whole-wave shift-right-by-1 of a double (two 32-bit DPPs, ctrl 0x138 =
// WAVE_SHR1). Lane 0 receives +0.0.
__device__ __forceinline__ double dpp_sr1_zero64(double x) {
    long long b = __double_as_longlong(x);
    int lo = (int)(b & 0xFFFFFFFFLL);
    int hi = (int)(b >> 32);
    int lo2 = __builtin_amdgcn_update_dpp(0, lo, 0x138, 0xF, 0xF, false);
    int hi2 = __builtin_amdgcn_update_dpp(0, hi, 0x138, 0xF, 0xF, false);
    return __longlong_as_double(((long long)hi2 << 32) |
                                (unsigned long long)(unsigned int)lo2);
}
// one level of DPP row-shr int max (identity 0; operands are >=0 hi-words)
template <int CTRL>
__device__ __forceinline__ int dpp_imax_level(int m) {
    int t = __builtin_amdgcn_update_dpp(0, m, CTRL, 0xF, 0xF, false);
    return m > t ? m : t;
}

// ---- fused prep: W column-norm + transpose to f16 (atomic-free, per-block
//      column ownership), feats row-normalize -> f16, and zeroing of
//      sumexp + ctc completion counter. Sectioned by blockIdx.x. ----
__global__ __launch_bounds__(256) void prep_kernel(const float* __restrict__ W,
                                                   const float* __restrict__ feats,
                                                   f16* __restrict__ wt,
                                                   f16* __restrict__ fn,
                                                   float* __restrict__ sumexp,
                                                   unsigned* __restrict__ ctr) {
    int bx = blockIdx.x, tid = threadIdx.x;
    if (bx < PREP_WBLK) {
        // ---- W-prep: this block owns 16 columns c0..c0+15 ----
        __shared__ float red[256];
        __shared__ float rqs[16];
        int c0 = bx * 16;
        int cl = tid & 15, dg = tid >> 4;
        int c = c0 + cl;
        float ss = 0.f;
        if (c < CC) {
            for (int d = dg; d < DD; d += 16) {
                float v = W[(size_t)d * CC + c];
                ss += v * v;
            }
        }
        red[tid] = ss;
        __syncthreads();
        if (tid < 16) {
            float s2 = 0.f;
            #pragma unroll
            for (int k = 0; k < 16; ++k) s2 += red[tid + 16 * k];
            rqs[tid] = rsqrtf(s2);
        }
        __syncthreads();
        // write wt[c][d] (f16), 16 consecutive-d lanes per c; W re-reads hit L1
        int c_loc = tid >> 4, dl = tid & 15;
        int cc = c0 + c_loc;
        float rq = rqs[c_loc];
        #pragma unroll 4
        for (int it = 0; it < 32; ++it) {
            int d = dl + it * 16;
            float v = (cc < CC) ? W[(size_t)d * CC + cc] * rq : 0.f;
            wt[(size_t)cc * DD + d] = (f16)v;
        }
    } else if (bx < PREP_WBLK + PREP_ZBLK) {
        int zb = bx - PREP_WBLK;
        if (zb < 16) {
            float4 z = {0.f, 0.f, 0.f, 0.f};
            ((float4*)sumexp)[zb * 256 + tid] = z;   // 16*256*16B = 64KB
        } else if (tid == 0) {
            *ctr = 0u;
        }
    } else {
        // ---- fnorm: one wave per feats row ----
        int fb = bx - PREP_WBLK - PREP_ZBLK;
        int wv = (fb * 256 + tid) >> 6;  // row id, 0..16383
        int lane = tid & 63;
        const float4* src = (const float4*)(feats + (size_t)wv * DD) + lane * 2;
        float4 a = src[0], b = src[1];
        float ss = a.x*a.x + a.y*a.y + a.z*a.z + a.w*a.w
                 + b.x*b.x + b.y*b.y + b.z*b.z + b.w*b.w;
        #pragma unroll
        for (int off = 32; off; off >>= 1) ss += __shfl_xor(ss, off);
        float r = rsqrtf(ss);
        f16x8 o;
        o[0]=(f16)(a.x*r); o[1]=(f16)(a.y*r); o[2]=(f16)(a.z*r); o[3]=(f16)(a.w*r);
        o[4]=(f16)(b.x*r); o[5]=(f16)(b.y*r); o[6]=(f16)(b.z*r); o[7]=(f16)(b.w*r);
        *(f16x8*)(fn + (size_t)wv * DD + lane * 8) = o;
    }
}

// ---- MFMA GEMM (A: 16384x512 f16, B^T: 1408x512 f16) with fused
//      row-wise sum(exp(32*dot)) epilogue -> atomicAdd into sumexp[16384].
//      LDS channel-slot XOR swizzle: (row,ch) stored at slot ch^((row>>1)&3). ----
__global__ __launch_bounds__(256) void gemm_sumexp_kernel(const f16* __restrict__ A,
                                                          const f16* __restrict__ B,
                                                          float* __restrict__ sumexp) {
    __shared__ __align__(16) f16 As[128 * 32];
    __shared__ __align__(16) f16 Bs[128 * 32];
    int bm = blockIdx.x, bn = blockIdx.y;
    int tid = threadIdx.x;
    int w = tid >> 6, lane = tid & 63;
    int wm = w >> 1, wn = w & 1;           // 2x2 wave grid -> 64x64 per wave
    int lm = lane & 15, hi = lane >> 4;
    int sw = (lm >> 1) & 3;                // fragment-read channel swizzle
    f32x4 acc[4][4];
    f32x4 zero = {0.f, 0.f, 0.f, 0.f};
    #pragma unroll
    for (int i = 0; i < 4; ++i)
        #pragma unroll
        for (int j = 0; j < 4; ++j) acc[i][j] = zero;

    for (int kb = 0; kb < 16; ++kb) {      // K=512, BK=32 (one MFMA K-step)
        #pragma unroll
        for (int p = 0; p < 2; ++p) {
            int s = p * 256 + tid;         // segment id, 16B each; 512 segs/tile
            int row = s >> 2;
            int ch = (s & 3) ^ ((row >> 1) & 3);   // swizzled source channel
            const f16* ga = A + (size_t)(bm * 128 + row) * DD + kb * 32 + ch * 8;
            const f16* gb = B + (size_t)(bn * 128 + row) * DD + kb * 32 + ch * 8;
            // LDS dest = wave-uniform base + lane*16 (contiguous, required)
            __builtin_amdgcn_global_load_lds((as1_void_ptr)ga,
                (as3_void_ptr)&As[(p * 256 + w * 64) * 8], 16, 0, 0);
            __builtin_amdgcn_global_load_lds((as1_void_ptr)gb,
                (as3_void_ptr)&Bs[(p * 256 + w * 64) * 8], 16, 0, 0);
        }
        __syncthreads();
        f16x8 af[4], bf[4];
        #pragma unroll
        for (int i = 0; i < 4; ++i)
            af[i] = *(const f16x8*)&As[(wm * 64 + i * 16 + lm) * 32 + (hi ^ sw) * 8];
        #pragma unroll
        for (int j = 0; j < 4; ++j)
            bf[j] = *(const f16x8*)&Bs[(wn * 64 + j * 16 + lm) * 32 + (hi ^ sw) * 8];
        #pragma unroll
        for (int i = 0; i < 4; ++i)
            #pragma unroll
            for (int j = 0; j < 4; ++j)
                acc[i][j] = __builtin_amdgcn_mfma_f32_16x16x32_f16(af[i], bf[j], acc[i][j], 0, 0, 0);
        __syncthreads();
    }
    // epilogue: per-row sum of exp(32*logit) over this block's 128 columns
    #pragma unroll
    for (int i = 0; i < 4; ++i) {
        float rs[4] = {0.f, 0.f, 0.f, 0.f};
        #pragma unroll
        for (int j = 0; j < 4; ++j) {
            int c = bn * 128 + wn * 64 + j * 16 + lm;   // C/D: col = lane&15
            bool ok = (c < CC);
            #pragma unroll
            for (int r = 0; r < 4; ++r)
                rs[r] += ok ? fexp2(acc[i][j][r] * (NORM_SCALE * LOG2E)) : 0.f;
        }
        #pragma unroll
        for (int off = 1; off < 16; off <<= 1) {        // sum over 16 cols
            #pragma unroll
            for (int r = 0; r < 4; ++r) rs[r] += __shfl_xor(rs[r], off);
        }
        if (lm == 0) {
            int rowb = bm * 128 + wm * 64 + i * 16 + hi * 4;  // row = quad*4+reg
            #pragma unroll
            for (int r = 0; r < 4; ++r) atomicAdd(&sumexp[rowb + r], rs[r]);
        }
    }
}

// ---- gather-GEMM (f16): per (n, 64-t chunk), P = Fn(64x512) x Wlab^T(32x512).
//      All 16 K-tiles staged up-front (A 64KB + B 32KB LDS), ONE barrier.
//      Same LDS channel-slot XOR swizzle as gemm. ----
__global__ __launch_bounds__(256) void gather_kernel(const f16* __restrict__ fn,
                                                     const f16* __restrict__ wt,
                                                     const float* __restrict__ sumexp,
                                                     const int* __restrict__ labels,
                                                     float* __restrict__ lp_lab) {
    __shared__ __align__(16) f16 Bs[16 * 32 * 32];   // 32 KB: [kb][row][slot]
    __shared__ __align__(16) f16 As[16 * 64 * 32];   // 64 KB: [kb][row][slot]
    __shared__ float ls2[64];
    int n = blockIdx.x, t0 = blockIdx.y * 64;
    int tid = threadIdx.x;
    int w = tid >> 6, lane = tid & 63;
    int lm = lane & 15, hi = lane >> 4;
    int sw = (lm >> 1) & 3;

    #pragma unroll
    for (int it = 0; it < 8; ++it) {       // B: 2048 segs of 16B
        int s = it * 256 + tid;            // kb = s>>7, row = (s>>2)&31
        int row = (s >> 2) & 31;
        int ch = (s & 3) ^ ((row >> 1) & 3);
        int cls = (row == 0 || row > SS) ? 0 : labels[n * SS + row - 1];
        const f16* gb = wt + (size_t)cls * DD + (s >> 7) * 32 + ch * 8;
        __builtin_amdgcn_global_load_lds((as1_void_ptr)gb,
            (as3_void_ptr)&Bs[(it * 256 + w * 64) * 8], 16, 0, 0);
    }
    #pragma unroll
    for (int it = 0; it < 16; ++it) {      // A: 4096 segs of 16B
        int s = it * 256 + tid;            // kb = s>>8, row = (s>>2)&63
        int kb = s >> 8, row = (s >> 2) & 63;
        int ch = (s & 3) ^ ((row >> 1) & 3);
        const f16* ga = fn + (size_t)((t0 + row) * NN + n) * DD + kb * 32 + ch * 8;
        __builtin_amdgcn_global_load_lds((as1_void_ptr)ga,
            (as3_void_ptr)&As[(it * 256 + w * 64) * 8], 16, 0, 0);
    }
    if (tid < 64) ls2[tid] = flog2(sumexp[(size_t)(t0 + tid) * NN + n]);
    __syncthreads();

    f32x4 acc[2];
    acc[0] = (f32x4){0.f, 0.f, 0.f, 0.f};
    acc[1] = (f32x4){0.f, 0.f, 0.f, 0.f};
    #pragma unroll
    for (int kb = 0; kb < 16; ++kb) {
        f16x8 af  = *(const f16x8*)&As[kb * 2048 + (w * 16 + lm) * 32 + (hi ^ sw) * 8];
        f16x8 bf0 = *(const f16x8*)&Bs[kb * 1024 + lm * 32 + (hi ^ sw) * 8];
        f16x8 bf1 = *(const f16x8*)&Bs[kb * 1024 + (16 + lm) * 32 + (hi ^ sw) * 8];
        acc[0] = __builtin_amdgcn_mfma_f32_16x16x32_f16(af, bf0, acc[0], 0, 0, 0);
        acc[1] = __builtin_amdgcn_mfma_f32_16x16x32_f16(af, bf1, acc[1], 0, 0, 0);
    }
    #pragma unroll
    for (int jn = 0; jn < 2; ++jn) {
        int j = jn * 16 + lm;
        if (j >= 31) continue;
        float* dst = lp_lab + ((size_t)n * 31 + j) * TT + t0;
        #pragma unroll
        for (int r = 0; r < 4; ++r) {
            int tl = w * 16 + hi * 4 + r;
            dst[tl] = acc[jn][r] * (NORM_SCALE * LOG2E) - ls2[tl];
        }
    }
}

// ---- CTC alpha recursion, LINEAR domain in f64: one wave/sample, lane=state.
//      beta = (b + b<<1 + skip*(b<<2)) * 2^lp; chain has no transcendentals.
//      Wave-uniform exact power-of-2 renorm every 4 steps (hi-word int max);
//      freeze handled by wave-uniform loop bound (Tin per-sample).
//      R12: last-finishing block performs the final deterministic sum
//      (fence + device-scope counter), removing the reduce dispatch. ----
__global__ void ctc_kernel(const float* __restrict__ lp_lab, const int* __restrict__ labels,
                           const int* __restrict__ in_lens, const int* __restrict__ lab_lens,
                           float* __restrict__ nll, unsigned* __restrict__ ctr,
                           float* __restrict__ out) {
    int n = blockIdx.x;
    int s = threadIdx.x;     // 64 lanes; states 0..60 valid
    bool valid = s < LL;
    int ext = (valid && (s & 1)) ? labels[n * SS + (s >> 1)] : 0;
    int jmap = (valid && (s & 1)) ? ((s >> 1) + 1) : 0;   // state -> class slot
    int ext2 = __shfl_up(ext, 2);
    double skipd = ((s >= 2) && valid && (ext != ext2)) ? 1.0 : 0.0;
    int Tin = in_lens[n];    // wave-uniform; freeze == stop at t = Tin-1
    const float4* g0 = (const float4*)(lp_lab + ((size_t)n * 31 + jmap) * TT);

    float4 cur = g0[0];
    float4 nxt = g0[1];
    float4 nx2 = g0[2];
    double beta = (s <= 1) ? (double)fexp2(cur.x) : 0.0;
    int Mi = 0;              // running log2 scale: alpha = log2(beta) + Mi

    auto stepL = [&](float lp) {
        double P = (double)fexp2(lp);      // lp >= ~-60 bits here: f32-safe
        double b1 = dpp_sr1_zero64(beta);
        double b2 = dpp_sr1_zero64(b1);
        beta = (beta + b1 + b2 * skipd) * P;
    };
    auto renorm = [&]() {
        int h = (int)(__double_as_longlong(beta) >> 32);  // beta>=0: monotone
        h = dpp_imax_level<0x111>(h);        // row_shr:1
        h = dpp_imax_level<0x112>(h);        // row_shr:2
        h = dpp_imax_level<0x114>(h);        // row_shr:4
        h = dpp_imax_level<0x118>(h);        // row_shr:8 -> row max in 15/31/47/63
        int r0 = __builtin_amdgcn_readlane(h, 15);
        int r1 = __builtin_amdgcn_readlane(h, 31);
        int r2 = __builtin_amdgcn_readlane(h, 47);
        int r3 = __builtin_amdgcn_readlane(h, 63);
        int mx = max(max(r0, r1), max(r2, r3));
        int e11 = mx >> 20;                  // biased 11-bit exponent
        // exact scale 2^(1023-(e11-1023)): biased exponent 2046-e11
        double scale = __longlong_as_double((long long)(2046 - e11) << 52);
        beta *= scale;
        Mi += e11 - 1023;
    };

    // group 0: t = 1..3 (Tin >= 481, always full)
    stepL(cur.y); stepL(cur.z); stepL(cur.w);
    renorm();
    int remaining = Tin - 4;   // steps left (total steps = Tin-1)
    int g = 1;
    while (remaining >= 4) {
        cur = nxt; nxt = nx2;
        int gi = g + 2; if (gi > 127) gi = 127;
        nx2 = g0[gi];
        stepL(cur.x); stepL(cur.y); stepL(cur.z); stepL(cur.w);
        renorm();
        remaining -= 4; ++g;
    }
    cur = nxt;                 // tail 0..3 steps
    if (remaining > 0) stepL(cur.x);
    if (remaining > 1) stepL(cur.y);
    if (remaining > 2) stepL(cur.z);

    int Ln = 2 * lab_lens[n] + 1;
    double last  = __shfl(beta, Ln - 1);
    double last2 = __shfl(beta, Ln - 2);
    double sm = last + last2;
    // log2 from the double's own exponent+mantissa (no tiny-f64 -> f32 cast)
    long long bb = __double_as_longlong(sm);
    int e = (int)(bb >> 52) - 1023;
    double mant = __longlong_as_double((bb & 0xFFFFFFFFFFFFFLL) | (1023LL << 52));
    float v = -(flog2((float)mant) + (float)(e + Mi)) * LN2;
    if (s == 0) {
        nll[n] = v;
        __threadfence();                       // publish nll[n] device-wide
        unsigned old = atomicAdd(ctr, 1u);     // device-scope by default
        if (old == NN - 1) {                   // last block: deterministic sum
            __threadfence();
            float t = 0.f;
            for (int i = 0; i < NN; ++i) t += nll[i];
            out[0] = t;
        }
    }
}

extern "C" void kernel_launch(void* const* d_in, const int* in_sizes, int n_in,
                              void* d_out, int out_size, void* d_ws, size_t ws_size,
                              hipStream_t stream) {
    const float* feats        = (const float*)d_in[0];
    const float* W            = (const float*)d_in[1];
    const int*   labeling     = (const int*)d_in[2];
    const int*   logit_lgts   = (const int*)d_in[3];
    const int*   labeling_lgts= (const int*)d_in[4];
    float* out = (float*)d_out;
    char* ws = (char*)d_ws;

    size_t off = 0;
    f16*   wt     = (f16*)(ws + off);   off += (size_t)CP * DD * 2;        // 1.44 MB
    f16*   fn     = (f16*)(ws + off);   off += (size_t)TT * NN * DD * 2;   // 16.8 MB
    float* sumexp = (float*)(ws + off); off += (size_t)TT * NN * 4;        // 64 KB
    float* lp_lab = (float*)(ws + off); off += (size_t)NN * 31 * TT * 4;   // 2.0 MB
    float* nllb   = (float*)(ws + off); off += 64 * 4;
    unsigned* ctr = (unsigned*)(ws + off); off += 64;

    prep_kernel<<<PREP_WBLK + PREP_ZBLK + PREP_FBLK, 256, 0, stream>>>(
        W, feats, wt, fn, sumexp, ctr);
    gemm_sumexp_kernel<<<dim3(TT * NN / 128, CP / 128), 256, 0, stream>>>(fn, wt, sumexp);
    gather_kernel<<<dim3(NN, TT / 64), 256, 0, stream>>>(fn, wt, sumexp, labeling, lp_lab);
    ctc_kernel<<<NN, 64, 0, stream>>>(lp_lab, labeling, logit_lgts, labeling_lgts,
                                      nllb, ctr, out);

    (void)in_sizes; (void)n_in; (void)out_size; (void)ws_size;
}

// Round 3
// 160.666 us; speedup vs baseline: 1.0167x; 1.0138x over previous
//
#include <hip/hip_runtime.h>
#include <stdint.h>
#include <stddef.h>

// RadialCTC: cosine logits (norm_scale=32) -> log_softmax -> CTC(sum).
// Strategy: never materialize the (16384 x 1296) logits. GEMM (f16 MFMA)
// computes per-row sum(exp(logit)) fused in the epilogue; label log-probs via
// small f16 MFMA gather-GEMM; CTC alpha recursion one wave per sample.
// R4: gather on MFMA. R9: linear f64 + pow2 renorm ctc (~30us). R10: gemm LDS
// 8-way conflicts found. R11: XOR channel-slot swizzle (kept), ~1us.
// R12: 9 -> 4 dispatches: NO CHANGE (163us) -> inter-node-gap theory dead;
// time = kernel sum + fixed replay floor. All kernels < 43.6us (top-5 fills).
// R14 (this round): factor log2(sumexp) OUT of the CTC recursion (it is
// state-independent): gather stores RAW scaled logits and no longer depends
// on gemm -> gather fused into the gemm dispatch as 256 tail blocks that
// backfill the gemm straggler tail (concurrent, not serial). Gather
// restructured from 96KB big-stage to 6KB K-looped stage so union LDS = 16KB
// (gemm occupancy unchanged). ctc computes Msum = sum_t flog2(sumexp[t]) in
// f64 off the beta chain and folds it into the final nll. 3 dispatches.

typedef _Float16 f16;
typedef _Float16 f16x8 __attribute__((ext_vector_type(8)));
typedef float f32x4 __attribute__((ext_vector_type(4)));
typedef __attribute__((address_space(1))) void* as1_void_ptr;
typedef __attribute__((address_space(3))) void* as3_void_ptr;

#define TT 512
#define NN 32
#define CC 1296
#define DD 512
#define SS 30
#define CP 1408   // C padded to 11*128 for GEMM tiling (pad rows are zero)
#define LL 61     // 2*S+1 CTC states
#define NORM_SCALE 32.0f
#define LOG2E 1.4426950408889634f
#define LN2   0.6931471805599453f

#define PREP_WBLK (CP / 16)            // 88 c-tiles of 16 (covers pad -> zeros)
#define PREP_ZBLK 17                   // 16 zero sumexp + 1 zero counter
#define PREP_FBLK (TT * NN / 4)        // 4096 fnorm blocks (4 rows each)

#define GEMM_BLK ((TT * NN / 128) * (CP / 128))   // 128*11 = 1408
#define GATH_BLK (NN * (TT / 64))                 // 32*8  = 256

__device__ __forceinline__ float fexp2(float x) { return __builtin_amdgcn_exp2f(x); }
__device__ __forceinline__ float flog2(float x) { return __builtin_amdgcn_logf(x); }

// whole-wave shift-right-by-1 of a double (two 32-bit DPPs, ctrl 0x138 =
// WAVE_SHR1). Lane 0 receives +0.0.
__device__ __forceinline__ double dpp_sr1_zero64(double x) {
    long long b = __double_as_longlong(x);
    int lo = (int)(b & 0xFFFFFFFFLL);
    int hi = (int)(b >> 32);
    int lo2 = __builtin_amdgcn_update_dpp(0, lo, 0x138, 0xF, 0xF, false);
    int hi2 = __builtin_amdgcn_update_dpp(0, hi, 0x138, 0xF, 0xF, false);
    return __longlong_as_double(((long long)hi2 << 32) |
                                (unsigned long long)(unsigned int)lo2);
}
// one level of DPP row-shr int max (identity 0; operands are >=0 hi-words)
template <int CTRL>
__device__ __forceinline__ int dpp_imax_level(int m) {
    int t = __builtin_amdgcn_update_dpp(0, m, CTRL, 0xF, 0xF, false);
    return m > t ? m : t;
}

// ---- fused prep: W column-norm + transpose to f16 (atomic-free, per-block
//      column ownership), feats row-normalize -> f16, and zeroing of
//      sumexp + ctc completion counter. Sectioned by blockIdx.x. ----
__global__ __launch_bounds__(256) void prep_kernel(const float* __restrict__ W,
                                                   const float* __restrict__ feats,
                                                   f16* __restrict__ wt,
                                                   f16* __restrict__ fn,
                                                   float* __restrict__ sumexp,
                                                   unsigned* __restrict__ ctr) {
    int bx = blockIdx.x, tid = threadIdx.x;
    if (bx < PREP_WBLK) {
        // ---- W-prep: this block owns 16 columns c0..c0+15 ----
        __shared__ float red[256];
        __shared__ float rqs[16];
        int c0 = bx * 16;
        int cl = tid & 15, dg = tid >> 4;
        int c = c0 + cl;
        float ss = 0.f;
        if (c < CC) {
            for (int d = dg; d < DD; d += 16) {
                float v = W[(size_t)d * CC + c];
                ss += v * v;
            }
        }
        red[tid] = ss;
        __syncthreads();
        if (tid < 16) {
            float s2 = 0.f;
            #pragma unroll
            for (int k = 0; k < 16; ++k) s2 += red[tid + 16 * k];
            rqs[tid] = rsqrtf(s2);
        }
        __syncthreads();
        // write wt[c][d] (f16), 16 consecutive-d lanes per c; W re-reads hit L1
        int c_loc = tid >> 4, dl = tid & 15;
        int cc = c0 + c_loc;
        float rq = rqs[c_loc];
        #pragma unroll 4
        for (int it = 0; it < 32; ++it) {
            int d = dl + it * 16;
            float v = (cc < CC) ? W[(size_t)d * CC + cc] * rq : 0.f;
            wt[(size_t)cc * DD + d] = (f16)v;
        }
    } else if (bx < PREP_WBLK + PREP_ZBLK) {
        int zb = bx - PREP_WBLK;
        if (zb < 16) {
            float4 z = {0.f, 0.f, 0.f, 0.f};
            ((float4*)sumexp)[zb * 256 + tid] = z;   // 16*256*16B = 64KB
        } else if (tid == 0) {
            *ctr = 0u;
        }
    } else {
        // ---- fnorm: one wave per feats row ----
        int fb = bx - PREP_WBLK - PREP_ZBLK;
        int wv = (fb * 256 + tid) >> 6;  // row id, 0..16383
        int lane = tid & 63;
        const float4* src = (const float4*)(feats + (size_t)wv * DD) + lane * 2;
        float4 a = src[0], b = src[1];
        float ss = a.x*a.x + a.y*a.y + a.z*a.z + a.w*a.w
                 + b.x*b.x + b.y*b.y + b.z*b.z + b.w*b.w;
        #pragma unroll
        for (int off = 32; off; off >>= 1) ss += __shfl_xor(ss, off);
        float r = rsqrtf(ss);
        f16x8 o;
        o[0]=(f16)(a.x*r); o[1]=(f16)(a.y*r); o[2]=(f16)(a.z*r); o[3]=(f16)(a.w*r);
        o[4]=(f16)(b.x*r); o[5]=(f16)(b.y*r); o[6]=(f16)(b.z*r); o[7]=(f16)(b.w*r);
        *(f16x8*)(fn + (size_t)wv * DD + lane * 8) = o;
    }
}

// ---- fused GEMM + gather dispatch.
//  Blocks [0, GEMM_BLK): MFMA GEMM (A: 16384x512 f16, B^T: 1408x512 f16) with
//    fused row-wise sum(exp(32*dot)) epilogue -> atomicAdd into sumexp.
//  Blocks [GEMM_BLK, +GATH_BLK): gather-GEMM per (n, 64-t chunk):
//    P_raw = Fn(64x512) x Wlab^T(32x512) * (32*log2e)  -- NO ls2 subtraction
//    (log2(sumexp) is state-independent; ctc folds it in via Msum).
//  Union LDS: 8192 f16 = 16 KB for both sections (gemm occupancy unchanged).
//  LDS channel-slot XOR swizzle: (row,ch) stored at slot ch^((row>>1)&3). ----
__global__ __launch_bounds__(256) void gg_kernel(const f16* __restrict__ A,
                                                 const f16* __restrict__ B,
                                                 const int* __restrict__ labels,
                                                 float* __restrict__ sumexp,
                                                 float* __restrict__ lp_lab) {
    __shared__ __align__(16) f16 sm[8192];   // 16 KB union
    int bx = blockIdx.x;
    int tid = threadIdx.x;
    int w = tid >> 6, lane = tid & 63;
    int lm = lane & 15, hi = lane >> 4;
    int sw = (lm >> 1) & 3;                // fragment-read channel swizzle

    if (bx < GEMM_BLK) {
        int bm = bx & 127, bn = bx >> 7;       // 1408 = 11 * 128
        int wm = w >> 1, wn = w & 1;           // 2x2 wave grid -> 64x64 per wave
        f32x4 acc[4][4];
        f32x4 zero = {0.f, 0.f, 0.f, 0.f};
        #pragma unroll
        for (int i = 0; i < 4; ++i)
            #pragma unroll
            for (int j = 0; j < 4; ++j) acc[i][j] = zero;

        for (int kb = 0; kb < 16; ++kb) {      // K=512, BK=32 (one MFMA K-step)
            #pragma unroll
            for (int p = 0; p < 2; ++p) {
                int s = p * 256 + tid;         // segment id, 16B each; 512 segs/tile
                int row = s >> 2;
                int ch = (s & 3) ^ ((row >> 1) & 3);   // swizzled source channel
                const f16* ga = A + (size_t)(bm * 128 + row) * DD + kb * 32 + ch * 8;
                const f16* gb = B + (size_t)(bn * 128 + row) * DD + kb * 32 + ch * 8;
                // LDS dest = wave-uniform base + lane*16 (contiguous, required)
                __builtin_amdgcn_global_load_lds((as1_void_ptr)ga,
                    (as3_void_ptr)&sm[(p * 256 + w * 64) * 8], 16, 0, 0);
                __builtin_amdgcn_global_load_lds((as1_void_ptr)gb,
                    (as3_void_ptr)&sm[4096 + (p * 256 + w * 64) * 8], 16, 0, 0);
            }
            __syncthreads();
            f16x8 af[4], bf[4];
            #pragma unroll
            for (int i = 0; i < 4; ++i)
                af[i] = *(const f16x8*)&sm[(wm * 64 + i * 16 + lm) * 32 + (hi ^ sw) * 8];
            #pragma unroll
            for (int j = 0; j < 4; ++j)
                bf[j] = *(const f16x8*)&sm[4096 + (wn * 64 + j * 16 + lm) * 32 + (hi ^ sw) * 8];
            #pragma unroll
            for (int i = 0; i < 4; ++i)
                #pragma unroll
                for (int j = 0; j < 4; ++j)
                    acc[i][j] = __builtin_amdgcn_mfma_f32_16x16x32_f16(af[i], bf[j], acc[i][j], 0, 0, 0);
            __syncthreads();
        }
        // epilogue: per-row sum of exp(32*logit) over this block's 128 columns
        #pragma unroll
        for (int i = 0; i < 4; ++i) {
            float rs[4] = {0.f, 0.f, 0.f, 0.f};
            #pragma unroll
            for (int j = 0; j < 4; ++j) {
                int c = bn * 128 + wn * 64 + j * 16 + lm;   // C/D: col = lane&15
                bool ok = (c < CC);
                #pragma unroll
                for (int r = 0; r < 4; ++r)
                    rs[r] += ok ? fexp2(acc[i][j][r] * (NORM_SCALE * LOG2E)) : 0.f;
            }
            #pragma unroll
            for (int off = 1; off < 16; off <<= 1) {        // sum over 16 cols
                #pragma unroll
                for (int r = 0; r < 4; ++r) rs[r] += __shfl_xor(rs[r], off);
            }
            if (lm == 0) {
                int rowb = bm * 128 + wm * 64 + i * 16 + hi * 4;  // row = quad*4+reg
                #pragma unroll
                for (int r = 0; r < 4; ++r) atomicAdd(&sumexp[rowb + r], rs[r]);
            }
        }
    } else {
        // ---- gather section: 6 KB LDS, K-looped stage ----
        int gbx = bx - GEMM_BLK;
        int n = gbx & 31, t0 = (gbx >> 5) * 64;
        // per-thread staging sources (constant across kb)
        int arow = tid >> 2;                       // 0..63 (A: 256 segs of 16B)
        int ach = (tid & 3) ^ ((arow >> 1) & 3);
        const f16* gaB = A + (size_t)((t0 + arow) * NN + n) * DD + ach * 8;
        int brow = tid >> 2;                       // valid for tid<128: 0..31
        int bch = (tid & 3) ^ ((brow >> 1) & 3);
        int cls = (brow == 0 || brow > SS) ? 0 : labels[n * SS + brow - 1];
        const f16* gbB = B + (size_t)cls * DD + bch * 8;

        f32x4 acc0 = {0.f, 0.f, 0.f, 0.f};
        f32x4 acc1 = {0.f, 0.f, 0.f, 0.f};
        for (int kb = 0; kb < 16; ++kb) {
            // A tile: 64 rows x 32 f16 -> sm[0..2047]; B tile: 32 rows -> sm[2048..3071]
            __builtin_amdgcn_global_load_lds((as1_void_ptr)(gaB + kb * 32),
                (as3_void_ptr)&sm[tid * 8], 16, 0, 0);
            if (tid < 128)
                __builtin_amdgcn_global_load_lds((as1_void_ptr)(gbB + kb * 32),
                    (as3_void_ptr)&sm[2048 + tid * 8], 16, 0, 0);
            __syncthreads();
            f16x8 af  = *(const f16x8*)&sm[(w * 16 + lm) * 32 + (hi ^ sw) * 8];
            f16x8 bf0 = *(const f16x8*)&sm[2048 + lm * 32 + (hi ^ sw) * 8];
            f16x8 bf1 = *(const f16x8*)&sm[2048 + (16 + lm) * 32 + (hi ^ sw) * 8];
            acc0 = __builtin_amdgcn_mfma_f32_16x16x32_f16(af, bf0, acc0, 0, 0, 0);
            acc1 = __builtin_amdgcn_mfma_f32_16x16x32_f16(af, bf1, acc1, 0, 0, 0);
            __syncthreads();
        }
        #pragma unroll
        for (int jn = 0; jn < 2; ++jn) {
            int j = jn * 16 + lm;
            if (j >= 31) continue;
            float* dst = lp_lab + ((size_t)n * 31 + j) * TT + t0;
            f32x4 av = jn ? acc1 : acc0;
            #pragma unroll
            for (int r = 0; r < 4; ++r) {
                int tl = w * 16 + hi * 4 + r;
                dst[tl] = av[r] * (NORM_SCALE * LOG2E);   // RAW (no ls2)
            }
        }
    }
}

// ---- CTC alpha recursion, LINEAR domain in f64: one wave/sample, lane=state.
//      beta = (b + b<<1 + skip*(b<<2)) * 2^raw; raw in [-46.2, +46.2] since
//      the state-independent log2(sumexp) is factored out (Msum, f64, off the
//      critical chain). Wave-uniform exact pow2 renorm every 4 steps (growth
//      <= 2^185 per group, f64 range +-1023 bits: safe). Last-finishing block
//      does the final deterministic sum (fence + counter). ----
__global__ void ctc_kernel(const float* __restrict__ lp_lab, const int* __restrict__ labels,
                           const int* __restrict__ in_lens, const int* __restrict__ lab_lens,
                           const float* __restrict__ sumexp,
                           float* __restrict__ nll, unsigned* __restrict__ ctr,
                           float* __restrict__ out) {
    int n = blockIdx.x;
    int s = threadIdx.x;     // 64 lanes; states 0..60 valid
    bool valid = s < LL;
    int ext = (valid && (s & 1)) ? labels[n * SS + (s >> 1)] : 0;
    int jmap = (valid && (s & 1)) ? ((s >> 1) + 1) : 0;   // state -> class slot
    int ext2 = __shfl_up(ext, 2);
    double skipd = ((s >= 2) && valid && (ext != ext2)) ? 1.0 : 0.0;
    int Tin = in_lens[n];    // wave-uniform; freeze == stop at t = Tin-1
    const float4* g0 = (const float4*)(lp_lab + ((size_t)n * 31 + jmap) * TT);

    float4 cur = g0[0];
    float4 nxt = g0[1];
    float4 nx2 = g0[2];
    double beta = (s <= 1) ? (double)fexp2(cur.x) : 0.0;
    int Mi = 0;              // running log2 scale: alpha_raw = log2(beta) + Mi

    auto stepL = [&](float lp) {
        double P = (double)fexp2(lp);      // |lp| <= ~46.2: f32-safe
        double b1 = dpp_sr1_zero64(beta);
        double b2 = dpp_sr1_zero64(b1);
        beta = (beta + b1 + b2 * skipd) * P;
    };
    auto renorm = [&]() {
        int h = (int)(__double_as_longlong(beta) >> 32);  // beta>=0: monotone
        h = dpp_imax_level<0x111>(h);        // row_shr:1
        h = dpp_imax_level<0x112>(h);        // row_shr:2
        h = dpp_imax_level<0x114>(h);        // row_shr:4
        h = dpp_imax_level<0x118>(h);        // row_shr:8 -> row max in 15/31/47/63
        int r0 = __builtin_amdgcn_readlane(h, 15);
        int r1 = __builtin_amdgcn_readlane(h, 31);
        int r2 = __builtin_amdgcn_readlane(h, 47);
        int r3 = __builtin_amdgcn_readlane(h, 63);
        int mx = max(max(r0, r1), max(r2, r3));
        int e11 = mx >> 20;                  // biased 11-bit exponent
        // exact scale 2^(1023-(e11-1023)): biased exponent 2046-e11
        double scale = __longlong_as_double((long long)(2046 - e11) << 52);
        beta *= scale;
        Mi += e11 - 1023;
    };

    // group 0: t = 1..3 (Tin >= 481, always full)
    stepL(cur.y); stepL(cur.z); stepL(cur.w);
    renorm();
    int remaining = Tin - 4;   // steps left (total steps = Tin-1)
    int g = 1;
    while (remaining >= 4) {
        cur = nxt; nxt = nx2;
        int gi = g + 2; if (gi > 127) gi = 127;
        nx2 = g0[gi];
        stepL(cur.x); stepL(cur.y); stepL(cur.z); stepL(cur.w);
        renorm();
        remaining -= 4; ++g;
    }
    cur = nxt;                 // tail 0..3 steps
    if (remaining > 0) stepL(cur.x);
    if (remaining > 1) stepL(cur.y);
    if (remaining > 2) stepL(cur.z);

    // Msum = sum_{t<Tin} log2(sumexp[t,n]) -- off the beta chain, f64 partials
    double ms = 0.0;
    for (int t = s; t < Tin; t += 64)
        ms += (double)flog2(sumexp[(size_t)t * NN + n]);
    #pragma unroll
    for (int off = 32; off; off >>= 1) ms += __shfl_xor(ms, off);

    int Ln = 2 * lab_lens[n] + 1;
    double last  = __shfl(beta, Ln - 1);
    double last2 = __shfl(beta, Ln - 2);
    double sm = last + last2;
    // log2 from the double's own exponent+mantissa (no tiny-f64 -> f32 cast)
    long long bb = __double_as_longlong(sm);
    int e = (int)(bb >> 52) - 1023;
    double mant = __longlong_as_double((bb & 0xFFFFFFFFFFFFFLL) | (1023LL << 52));
    float v = (float)(-((double)flog2((float)mant) + (double)(e + Mi) - ms) * LN2);
    if (s == 0) {
        nll[n] = v;
        __threadfence();                       // publish nll[n] device-wide
        unsigned old = atomicAdd(ctr, 1u);     // device-scope by default
        if (old == NN - 1) {                   // last block: deterministic sum
            __threadfence();
            float t = 0.f;
            for (int i = 0; i < NN; ++i) t += nll[i];
            out[0] = t;
        }
    }
}

extern "C" void kernel_launch(void* const* d_in, const int* in_sizes, int n_in,
                              void* d_out, int out_size, void* d_ws, size_t ws_size,
                              hipStream_t stream) {
    const float* feats        = (const float*)d_in[0];
    const float* W            = (const float*)d_in[1];
    const int*   labeling     = (const int*)d_in[2];
    const int*   logit_lgts   = (const int*)d_in[3];
    const int*   labeling_lgts= (const int*)d_in[4];
    float* out = (float*)d_out;
    char* ws = (char*)d_ws;

    size_t off = 0;
    f16*   wt     = (f16*)(ws + off);   off += (size_t)CP * DD * 2;        // 1.44 MB
    f16*   fn     = (f16*)(ws + off);   off += (size_t)TT * NN * DD * 2;   // 16.8 MB
    float* sumexp = (float*)(ws + off); off += (size_t)TT * NN * 4;        // 64 KB
    float* lp_lab = (float*)(ws + off); off += (size_t)NN * 31 * TT * 4;   // 2.0 MB
    float* nllb   = (float*)(ws + off); off += 64 * 4;
    unsigned* ctr = (unsigned*)(ws + off); off += 64;

    prep_kernel<<<PREP_WBLK + PREP_ZBLK + PREP_FBLK, 256, 0, stream>>>(
        W, feats, wt, fn, sumexp, ctr);
    gg_kernel<<<GEMM_BLK + GATH_BLK, 256, 0, stream>>>(fn, wt, labeling, sumexp, lp_lab);
    ctc_kernel<<<NN, 64, 0, stream>>>(lp_lab, labeling, logit_lgts, labeling_lgts,
                                      sumexp, nllb, ctr, out);

    (void)in_sizes; (void)n_in; (void)out_size; (void)ws_size;
}